// Round 1
// baseline (35546.222 us; speedup 1.0000x reference)
//
#include <hip/hip_runtime.h>

#define TSEQ 2048
#define NB   64
#define IND  256
#define HD   512

typedef unsigned int u32;
typedef unsigned long long u64;

using half8 = __attribute__((ext_vector_type(8))) _Float16;
using f32x4 = __attribute__((ext_vector_type(4))) float;

#define NWG_L1 64
#define NWG_L2 128
#define NWG    (NWG_L1 + NWG_L2)

// ws layout (bytes)
#define WS_FLAGS 0                     // u32[256]
#define WS_H1    2048                  // [2][64][512] f16 = 131072
#define WS_H2    (2048 + 131072)
#define WS_END   (2048 + 262144)

#define LDS_BYTES 153088

__device__ __forceinline__ float sigmoidf_(float x) { return 1.0f / (1.0f + __expf(-x)); }
__device__ __forceinline__ float tanhf_(float x) {
    float ax = __builtin_fabsf(x);
    float e  = __expf(-2.0f * ax);
    float t  = (1.0f - e) / (1.0f + e);
    return x >= 0.0f ? t : -t;
}

__device__ __forceinline__ u64 ld_agent_u64(const u64* p) {
    return __hip_atomic_load((u64*)p, __ATOMIC_RELAXED, __HIP_MEMORY_SCOPE_AGENT);
}
__device__ __forceinline__ void st_agent_u64(u64* p, u64 v) {
    __hip_atomic_store(p, v, __ATOMIC_RELAXED, __HIP_MEMORY_SCOPE_AGENT);
}
__device__ __forceinline__ u32 ld_flag_acq(u32* p) {
    return __hip_atomic_load(p, __ATOMIC_ACQUIRE, __HIP_MEMORY_SCOPE_AGENT);
}
__device__ __forceinline__ void st_flag_rel(u32* p, u32 v) {
    __hip_atomic_store(p, v, __ATOMIC_RELEASE, __HIP_MEMORY_SCOPE_AGENT);
}

// ---------------- init: zero flags + h buffers (sc-bypass so main's bypass loads see zeros), out = fc_b ----------------
__global__ void gru_init(u32* ws32, float* out, const float* fcb) {
    size_t n = WS_END / 4;
    size_t i = (size_t)blockIdx.x * blockDim.x + threadIdx.x;
    size_t stride = (size_t)gridDim.x * blockDim.x;
    for (; i < n; i += stride)
        __hip_atomic_store(ws32 + i, 0u, __ATOMIC_RELAXED, __HIP_MEMORY_SCOPE_AGENT);
    if (blockIdx.x == 0 && threadIdx.x < NB) {
        u32 b = __float_as_uint(fcb[0]);
        __hip_atomic_store((u32*)out + threadIdx.x, b, __ATOMIC_RELAXED, __HIP_MEMORY_SCOPE_AGENT);
    }
}

// ---------------- persistent GRU ----------------
__global__ void __launch_bounds__(384, 1) gru_main(
    const float* __restrict__ x,
    const float* __restrict__ wih0, const float* __restrict__ whh0,
    const float* __restrict__ bih0, const float* __restrict__ bhh0,
    const float* __restrict__ wih1, const float* __restrict__ whh1,
    const float* __restrict__ bih1, const float* __restrict__ bhh1,
    const float* __restrict__ fcw,
    float* __restrict__ out, char* __restrict__ ws)
{
    extern __shared__ char smem[];
    u32* flags = (u32*)(ws + WS_FLAGS);
    u64* h1    = (u64*)(ws + WS_H1);   // [2][64][128] u64 view of f16
    u64* h2    = (u64*)(ws + WS_H2);

    const int tid  = threadIdx.x;
    const int lane = tid & 63;
    const int wave = tid >> 6;
    const int bid  = blockIdx.x;
    const bool isL1 = bid < NWG_L1;
    const int g  = isL1 ? (bid >> 4) : ((bid - NWG_L1) >> 5);
    const int m0 = g * 16;
    const int row = lane & 15;   // batch row within tile (A-operand row)
    const int kb  = lane >> 4;   // k-block 0..3

    u32* myflag = flags + bid;
    // direct-poll set: 16 L1 flags + 32 L2 flags of this batch-group
    u32* fp = nullptr;
    if (lane < 16)      fp = flags + (g * 16 + lane);
    else if (lane < 48) fp = flags + (NWG_L1 + g * 32 + (lane - 16));

    if (isL1) {
        const int slice = bid & 15;
        const int hs    = slice * 32;

        half8*    frag   = (half8*)smem;                    // [6][24][64] B-frags
        float*    rz     = (float*)(smem + 147456);         // [2][32][16]
        _Float16* hstage = (_Float16*)(smem + 151552);      // [16][32]
        float*    bsum   = (float*)(smem + 152576);         // r(32), z(32)
        float*    bnih   = bsum + 64;                       // [32]
        float*    bnhh   = bnih + 32;                       // [32]

        // ---- pack weights (f16) into LDS in fragment order ----
        for (int idx = tid; idx < 6 * 24 * 64; idx += 384) {
            int t_ = idx / (24 * 64);
            int ks = (idx / 64) % 24;
            int l  = idx & 63;
            int nl = t_ * 16 + (l & 15);       // local gate-row 0..95
            int gate = nl >> 5;
            int c    = nl & 31;
            int R    = gate * 512 + hs + c;
            half8 w8;
            #pragma unroll
            for (int j = 0; j < 8; ++j) {
                int k = ks * 32 + (l >> 4) * 8 + j;
                float v = (k < IND) ? wih0[(size_t)R * IND + k]
                                    : whh0[(size_t)R * HD + (k - IND)];
                w8[j] = (_Float16)v;
            }
            frag[idx] = w8;
        }
        if (tid < 32) {
            bsum[tid]      = bih0[hs + tid] + bhh0[hs + tid];
            bsum[32 + tid] = bih0[512 + hs + tid] + bhh0[512 + hs + tid];
            bnih[tid]      = bih0[1024 + hs + tid];
            bnhh[tid]      = bhh0[1024 + hs + tid];
        }
        __syncthreads();

        const int tile = wave;       // 0..5 (one 16-col output tile each)
        const int gate = tile >> 1;  // 0=r, 1=z, 2=n

        const float* xrow = x + (size_t)(m0 + row) * (TSEQ * IND);
        float4 xv[16];
        #pragma unroll
        for (int ks = 0; ks < 8; ++ks) {
            const float4* p = (const float4*)(xrow + ks * 32 + kb * 8);
            xv[2 * ks]     = p[0];
            xv[2 * ks + 1] = p[1];
        }
        f32x4 hprev = {0.f, 0.f, 0.f, 0.f};

        for (int s = 0; s < TSEQ; ++s) {
            if (wave == 0 && s > 0) {
                while (1) {
                    u32 f = fp ? ld_flag_acq(fp) : 0xFFFFFFFFu;
                    if (__all((int)(f >= (u32)s))) break;
                    __builtin_amdgcn_s_sleep(1);
                }
            }
            __syncthreads();

            // issue h1[s-1] A-loads (sc-bypass; buffer (s-1)&1 == (s+1)&1)
            const u64* hb = h1 + ((size_t)((s + 1) & 1)) * 8192 + (size_t)(m0 + row) * 128;
            u64 hq[16][2];
            #pragma unroll
            for (int k8 = 0; k8 < 16; ++k8) {
                const u64* p = hb + k8 * 8 + kb * 2;
                hq[k8][0] = ld_agent_u64(p);
                hq[k8][1] = ld_agent_u64(p + 1);
            }

            // x-part MFMAs (k 0..255)
            f32x4 accA = {0.f, 0.f, 0.f, 0.f};
            f32x4 accB = {0.f, 0.f, 0.f, 0.f};
            #pragma unroll
            for (int ks = 0; ks < 8; ++ks) {
                float4 u = xv[2 * ks], v = xv[2 * ks + 1];
                half8 a = { (_Float16)u.x, (_Float16)u.y, (_Float16)u.z, (_Float16)u.w,
                            (_Float16)v.x, (_Float16)v.y, (_Float16)v.z, (_Float16)v.w };
                accA = __builtin_amdgcn_mfma_f32_16x16x32_f16(a, frag[(tile * 24 + ks) * 64 + lane], accA, 0, 0, 0);
            }
            // prefetch next x while h-part runs
            if (s + 1 < TSEQ) {
                #pragma unroll
                for (int ks = 0; ks < 8; ++ks) {
                    const float4* p = (const float4*)(xrow + (size_t)(s + 1) * IND + ks * 32 + kb * 8);
                    xv[2 * ks]     = p[0];
                    xv[2 * ks + 1] = p[1];
                }
            }
            // h-part MFMAs (k 256..767)
            #pragma unroll
            for (int k8 = 0; k8 < 16; ++k8) {
                union { u64 q[2]; half8 h; } ua;
                ua.q[0] = hq[k8][0]; ua.q[1] = hq[k8][1];
                if (gate == 2)
                    accB = __builtin_amdgcn_mfma_f32_16x16x32_f16(ua.h, frag[(tile * 24 + 8 + k8) * 64 + lane], accB, 0, 0, 0);
                else
                    accA = __builtin_amdgcn_mfma_f32_16x16x32_f16(ua.h, frag[(tile * 24 + 8 + k8) * 64 + lane], accA, 0, 0, 0);
            }

            // epilogue: r/z -> LDS, then n-waves update h
            if (gate < 2) {
                int c = (tile & 1) * 16 + (lane & 15);
                #pragma unroll
                for (int q = 0; q < 4; ++q) {
                    float pre = accA[q] + bsum[gate * 32 + c];
                    rz[gate * 512 + c * 16 + kb * 4 + q] = sigmoidf_(pre);
                }
            }
            __syncthreads();
            if (gate == 2) {
                int c = (tile - 4) * 16 + (lane & 15);
                #pragma unroll
                for (int q = 0; q < 4; ++q) {
                    int m = kb * 4 + q;
                    float r = rz[c * 16 + m];
                    float z = rz[512 + c * 16 + m];
                    float n = tanhf_(accA[q] + bnih[c] + r * (accB[q] + bnhh[c]));
                    float hn = (1.f - z) * n + z * hprev[q];
                    hprev[q] = hn;
                    hstage[m * 32 + c] = (_Float16)hn;
                }
            }
            __syncthreads();
            if (wave == 4) {
                int r_ = lane >> 2, ch = lane & 3;
                const u64* src = (const u64*)(hstage + r_ * 32 + ch * 8);
                u64* dst = h1 + ((size_t)(s & 1)) * 8192 + (size_t)(m0 + r_) * 128 + slice * 8 + ch * 2;
                st_agent_u64(dst,     src[0]);
                st_agent_u64(dst + 1, src[1]);
                if (lane == 0) st_flag_rel(myflag, (u32)(s + 1));
            }
        }
    } else {
        // ---------------- layer 2 ----------------
        const int lbid  = bid - NWG_L1;
        const int slice = lbid & 31;
        const int hs    = slice * 16;

        half8*    frag   = (half8*)smem;                    // [3][32][64]
        float*    part   = (float*)(smem + 98304);          // [3][16][16]
        float*    rz     = (float*)(smem + 101376);         // [2][16][16]
        _Float16* hstage = (_Float16*)(smem + 103424);      // [16][16]
        float*    bsum   = (float*)(smem + 103936);         // r(16), z(16)
        float*    bnih   = bsum + 32;                       // [16]
        float*    bnhh   = bnih + 16;                       // [16]
        float*    fcs    = bnhh + 16;                       // [16]

        if (tid == 0) st_flag_rel(myflag, 1u);  // "step 0 done"

        for (int idx = tid; idx < 3 * 32 * 64; idx += 384) {
            int t_ = idx / (32 * 64);
            int ks = (idx / 64) & 31;
            int l  = idx & 63;
            int R  = t_ * 512 + hs + (l & 15);
            half8 w8;
            #pragma unroll
            for (int j = 0; j < 8; ++j) {
                int k = ks * 32 + (l >> 4) * 8 + j;
                float v = (k < HD) ? wih1[(size_t)R * HD + k]
                                   : whh1[(size_t)R * HD + (k - HD)];
                w8[j] = (_Float16)v;
            }
            frag[idx] = w8;
        }
        if (tid < 16) {
            bsum[tid]      = bih1[hs + tid] + bhh1[hs + tid];
            bsum[16 + tid] = bih1[512 + hs + tid] + bhh1[512 + hs + tid];
            bnih[tid]      = bih1[1024 + hs + tid];
            bnhh[tid]      = bhh1[1024 + hs + tid];
            fcs[tid]       = fcw[hs + tid];
        }
        __syncthreads();

        const int gate = wave >> 1;   // 0=r,1=z,2=n
        const int half = wave & 1;    // 0: k from h1 (input), 1: k from h2 (recurrent)
        f32x4 hprev = {0.f, 0.f, 0.f, 0.f};

        for (int s = 1; s <= TSEQ; ++s) {
            if (wave == 0) {
                while (1) {
                    u32 f = fp ? ld_flag_acq(fp) : 0xFFFFFFFFu;
                    if (__all((int)(f >= (u32)s))) break;
                    __builtin_amdgcn_s_sleep(1);
                }
            }
            __syncthreads();

            u64 hq[16][2];
            if (half == 0) {
                const u64* hb = h1 + ((size_t)((s + 1) & 1)) * 8192 + (size_t)(m0 + row) * 128;
                #pragma unroll
                for (int k8 = 0; k8 < 16; ++k8) {
                    const u64* p = hb + k8 * 8 + kb * 2;
                    hq[k8][0] = ld_agent_u64(p);
                    hq[k8][1] = ld_agent_u64(p + 1);
                }
            } else {
                const u64* hb = h2 + ((size_t)(s & 1)) * 8192 + (size_t)(m0 + row) * 128;
                #pragma unroll
                for (int k8 = 0; k8 < 16; ++k8) {
                    const u64* p = hb + k8 * 8 + kb * 2;
                    hq[k8][0] = ld_agent_u64(p);
                    hq[k8][1] = ld_agent_u64(p + 1);
                }
            }
            f32x4 acc = {0.f, 0.f, 0.f, 0.f};
            #pragma unroll
            for (int k8 = 0; k8 < 16; ++k8) {
                union { u64 q[2]; half8 h; } ua;
                ua.q[0] = hq[k8][0]; ua.q[1] = hq[k8][1];
                acc = __builtin_amdgcn_mfma_f32_16x16x32_f16(ua.h, frag[(gate * 32 + half * 16 + k8) * 64 + lane], acc, 0, 0, 0);
            }

            if (half == 1) {
                int c = lane & 15;
                #pragma unroll
                for (int q = 0; q < 4; ++q) part[gate * 256 + c * 16 + kb * 4 + q] = acc[q];
            }
            __syncthreads();
            if (wave == 0 || wave == 2) {
                int c = lane & 15;
                #pragma unroll
                for (int q = 0; q < 4; ++q) {
                    int m = kb * 4 + q;
                    float pre = acc[q] + part[gate * 256 + c * 16 + m] + bsum[gate * 16 + c];
                    rz[gate * 256 + c * 16 + m] = sigmoidf_(pre);
                }
            }
            __syncthreads();
            if (wave == 4) {
                int c = lane & 15;
                #pragma unroll
                for (int q = 0; q < 4; ++q) {
                    int m = kb * 4 + q;
                    float r = rz[c * 16 + m];
                    float z = rz[256 + c * 16 + m];
                    float n = tanhf_(acc[q] + bnih[c] + r * (part[512 + c * 16 + m] + bnhh[c]));
                    float hn = (1.f - z) * n + z * hprev[q];
                    hprev[q] = hn;
                    hstage[m * 16 + c] = (_Float16)hn;
                }
                if (s == TSEQ) {
                    #pragma unroll
                    for (int q = 0; q < 4; ++q) {
                        float v = hprev[q] * fcs[lane & 15];
                        #pragma unroll
                        for (int off = 1; off < 16; off <<= 1)
                            v += __shfl_xor(v, off, 64);
                        if ((lane & 15) == 0) atomicAdd(out + m0 + kb * 4 + q, v);
                    }
                }
            }
            __syncthreads();
            if (wave == 0 && s < TSEQ) {
                int r_ = lane >> 2, ch = lane & 3;
                u64 v = *(const u64*)(hstage + r_ * 16 + ch * 4);
                u64* dst = h2 + ((size_t)((s + 1) & 1)) * 8192 + (size_t)(m0 + r_) * 128 + slice * 4 + ch;
                st_agent_u64(dst, v);
                if (lane == 0) st_flag_rel(myflag, (u32)(s + 1));
            }
        }
    }
}

extern "C" void kernel_launch(void* const* d_in, const int* in_sizes, int n_in,
                              void* d_out, int out_size, void* d_ws, size_t ws_size,
                              hipStream_t stream) {
    (void)in_sizes; (void)n_in; (void)out_size; (void)ws_size;
    const float* x    = (const float*)d_in[0];
    const float* wih0 = (const float*)d_in[1];
    const float* whh0 = (const float*)d_in[2];
    const float* bih0 = (const float*)d_in[3];
    const float* bhh0 = (const float*)d_in[4];
    const float* wih1 = (const float*)d_in[5];
    const float* whh1 = (const float*)d_in[6];
    const float* bih1 = (const float*)d_in[7];
    const float* bhh1 = (const float*)d_in[8];
    const float* fcw  = (const float*)d_in[9];
    const float* fcb  = (const float*)d_in[10];
    float* out = (float*)d_out;
    char* ws = (char*)d_ws;

    hipFuncSetAttribute((const void*)gru_main, hipFuncAttributeMaxDynamicSharedMemorySize, LDS_BYTES);

    gru_init<<<64, 256, 0, stream>>>((u32*)ws, out, fcb);
    gru_main<<<NWG, 384, LDS_BYTES, stream>>>(x, wih0, whh0, bih0, bhh0,
                                              wih1, whh1, bih1, bhh1, fcw, out, ws);
}

// Round 2
// 23757.860 us; speedup vs baseline: 1.4962x; 1.4962x over previous
//
#include <hip/hip_runtime.h>

#define TSEQ 2048
#define NB   64
#define IND  256
#define HD   512

typedef unsigned int u32;
typedef unsigned long long u64;

using half8 = __attribute__((ext_vector_type(8))) _Float16;
using f32x4 = __attribute__((ext_vector_type(4))) float;

#define NWG_L1 64
#define NWG_L2 128
#define NWG    (NWG_L1 + NWG_L2)

// ws layout (bytes)
#define WS_FLAGS 0                     // u32[256]
#define WS_H1    2048                  // [4][64][512] f16 = 262144
#define WS_H2    (2048 + 262144)
#define WS_END   (2048 + 524288)

#define LDS_BYTES 153088

__device__ __forceinline__ float sigmoidf_(float x) { return 1.0f / (1.0f + __expf(-x)); }
__device__ __forceinline__ float tanhf_(float x) {
    float ax = __builtin_fabsf(x);
    float e  = __expf(-2.0f * ax);
    float t  = (1.0f - e) / (1.0f + e);
    return x >= 0.0f ? t : -t;
}

// All cross-WG data moves through relaxed agent-scope atomics (sc1-flagged,
// serviced at the coherence point / L3). NO acquire/release: agent acquire
// emits buffer_inv (whole-L2 invalidate) per poll iteration and release emits
// an L2 writeback — round-1 counters showed this costs 12x HBM over-fetch and
// ~10x wall time. Ordering is done with explicit s_waitcnt vmcnt(0).
__device__ __forceinline__ u64 ld_agent_u64(const u64* p) {
    return __hip_atomic_load((u64*)p, __ATOMIC_RELAXED, __HIP_MEMORY_SCOPE_AGENT);
}
__device__ __forceinline__ void st_agent_u64(u64* p, u64 v) {
    __hip_atomic_store(p, v, __ATOMIC_RELAXED, __HIP_MEMORY_SCOPE_AGENT);
}
__device__ __forceinline__ u32 ld_flag(u32* p) {
    return __hip_atomic_load(p, __ATOMIC_RELAXED, __HIP_MEMORY_SCOPE_AGENT);
}
__device__ __forceinline__ void st_flag_fenced(u32* p, u32 v) {
    // drain all outstanding vmem stores to the coherence point, then publish
    asm volatile("s_waitcnt vmcnt(0)" ::: "memory");
    __hip_atomic_store(p, v, __ATOMIC_RELAXED, __HIP_MEMORY_SCOPE_AGENT);
}

// ---------------- init: zero flags + h buffers, out = fc_b ----------------
__global__ void gru_init(u32* ws32, float* out, const float* fcb) {
    size_t n = WS_END / 4;
    size_t i = (size_t)blockIdx.x * blockDim.x + threadIdx.x;
    size_t stride = (size_t)gridDim.x * blockDim.x;
    for (; i < n; i += stride)
        __hip_atomic_store(ws32 + i, 0u, __ATOMIC_RELAXED, __HIP_MEMORY_SCOPE_AGENT);
    if (blockIdx.x == 0 && threadIdx.x < NB) {
        u32 b = __float_as_uint(fcb[0]);
        __hip_atomic_store((u32*)out + threadIdx.x, b, __ATOMIC_RELAXED, __HIP_MEMORY_SCOPE_AGENT);
    }
}

// ---------------- persistent GRU ----------------
__global__ void __launch_bounds__(384, 1) gru_main(
    const float* __restrict__ x,
    const float* __restrict__ wih0, const float* __restrict__ whh0,
    const float* __restrict__ bih0, const float* __restrict__ bhh0,
    const float* __restrict__ wih1, const float* __restrict__ whh1,
    const float* __restrict__ bih1, const float* __restrict__ bhh1,
    const float* __restrict__ fcw,
    float* __restrict__ out, char* __restrict__ ws)
{
    extern __shared__ char smem[];
    u32* flags = (u32*)(ws + WS_FLAGS);
    u64* h1    = (u64*)(ws + WS_H1);   // [4][64][128] u64 view of f16
    u64* h2    = (u64*)(ws + WS_H2);

    const int tid  = threadIdx.x;
    const int lane = tid & 63;
    const int wave = tid >> 6;
    const int bid  = blockIdx.x;
    const bool isL1 = bid < NWG_L1;
    const int g  = isL1 ? (bid >> 4) : ((bid - NWG_L1) >> 5);
    const int m0 = g * 16;
    const int row = lane & 15;   // batch row within tile (A-operand row)
    const int kb  = lane >> 4;   // k-block 0..3

    u32* myflag = flags + bid;
    // direct-poll set: 16 L1 flags + 32 L2 flags of this batch-group
    u32* fp = nullptr;
    if (lane < 16)      fp = flags + (g * 16 + lane);
    else if (lane < 48) fp = flags + (NWG_L1 + g * 32 + (lane - 16));

    if (isL1) {
        const int slice = bid & 15;
        const int hs    = slice * 32;

        half8*    frag   = (half8*)smem;                    // [6][24][64] B-frags
        float*    rz     = (float*)(smem + 147456);         // [2][32][16]
        _Float16* hstage = (_Float16*)(smem + 151552);      // [16][32]
        float*    bsum   = (float*)(smem + 152576);         // r(32), z(32)
        float*    bnih   = bsum + 64;                       // [32]
        float*    bnhh   = bnih + 32;                       // [32]

        // ---- pack weights (f16) into LDS in fragment order ----
        for (int idx = tid; idx < 6 * 24 * 64; idx += 384) {
            int t_ = idx / (24 * 64);
            int ks = (idx / 64) % 24;
            int l  = idx & 63;
            int nl = t_ * 16 + (l & 15);       // local gate-row 0..95
            int gate = nl >> 5;
            int c    = nl & 31;
            int R    = gate * 512 + hs + c;
            half8 w8;
            #pragma unroll
            for (int j = 0; j < 8; ++j) {
                int k = ks * 32 + (l >> 4) * 8 + j;
                float v = (k < IND) ? wih0[(size_t)R * IND + k]
                                    : whh0[(size_t)R * HD + (k - IND)];
                w8[j] = (_Float16)v;
            }
            frag[idx] = w8;
        }
        if (tid < 32) {
            bsum[tid]      = bih0[hs + tid] + bhh0[hs + tid];
            bsum[32 + tid] = bih0[512 + hs + tid] + bhh0[512 + hs + tid];
            bnih[tid]      = bih0[1024 + hs + tid];
            bnhh[tid]      = bhh0[1024 + hs + tid];
        }
        __syncthreads();

        const int tile = wave;       // 0..5 (one 16-col output tile each)
        const int gate = tile >> 1;  // 0=r, 1=z, 2=n

        const float* xrow = x + (size_t)(m0 + row) * (TSEQ * IND);
        float4 xv[16];
        #pragma unroll
        for (int ks = 0; ks < 8; ++ks) {
            const float4* p = (const float4*)(xrow + ks * 32 + kb * 8);
            xv[2 * ks]     = p[0];
            xv[2 * ks + 1] = p[1];
        }
        f32x4 hprev = {0.f, 0.f, 0.f, 0.f};

        for (int s = 0; s < TSEQ; ++s) {
            if (wave == 0 && s > 0) {
                // peers (lanes 0-15): need their h1 slice of step s-1 -> flag >= s
                // L2 WGs (lanes 16-47): anti-dep on 4-deep buffer only -> flag >= s-2
                int thr = (lane < 16) ? s : (s - 2);
                while (1) {
                    int f = fp ? (int)ld_flag(fp) : 0x7FFFFFFF;
                    if (__all(f >= thr)) break;
                    __builtin_amdgcn_s_sleep(1);
                }
                asm volatile("" ::: "memory");
            }
            __syncthreads();

            // issue h1[s-1] A-loads (buffer (s-1)&3)
            const u64* hb = h1 + ((size_t)((s + 3) & 3)) * 8192 + (size_t)(m0 + row) * 128;
            u64 hq[16][2];
            #pragma unroll
            for (int k8 = 0; k8 < 16; ++k8) {
                const u64* p = hb + k8 * 8 + kb * 2;
                hq[k8][0] = ld_agent_u64(p);
                hq[k8][1] = ld_agent_u64(p + 1);
            }

            // x-part MFMAs (k 0..255)
            f32x4 accA = {0.f, 0.f, 0.f, 0.f};
            f32x4 accB = {0.f, 0.f, 0.f, 0.f};
            #pragma unroll
            for (int ks = 0; ks < 8; ++ks) {
                float4 u = xv[2 * ks], v = xv[2 * ks + 1];
                half8 a = { (_Float16)u.x, (_Float16)u.y, (_Float16)u.z, (_Float16)u.w,
                            (_Float16)v.x, (_Float16)v.y, (_Float16)v.z, (_Float16)v.w };
                accA = __builtin_amdgcn_mfma_f32_16x16x32_f16(a, frag[(tile * 24 + ks) * 64 + lane], accA, 0, 0, 0);
            }
            // prefetch next x while h-part runs
            if (s + 1 < TSEQ) {
                #pragma unroll
                for (int ks = 0; ks < 8; ++ks) {
                    const float4* p = (const float4*)(xrow + (size_t)(s + 1) * IND + ks * 32 + kb * 8);
                    xv[2 * ks]     = p[0];
                    xv[2 * ks + 1] = p[1];
                }
            }
            // h-part MFMAs (k 256..767)
            #pragma unroll
            for (int k8 = 0; k8 < 16; ++k8) {
                union { u64 q[2]; half8 h; } ua;
                ua.q[0] = hq[k8][0]; ua.q[1] = hq[k8][1];
                if (gate == 2)
                    accB = __builtin_amdgcn_mfma_f32_16x16x32_f16(ua.h, frag[(tile * 24 + 8 + k8) * 64 + lane], accB, 0, 0, 0);
                else
                    accA = __builtin_amdgcn_mfma_f32_16x16x32_f16(ua.h, frag[(tile * 24 + 8 + k8) * 64 + lane], accA, 0, 0, 0);
            }

            // epilogue: r/z -> LDS, then n-waves update h
            if (gate < 2) {
                int c = (tile & 1) * 16 + (lane & 15);
                #pragma unroll
                for (int q = 0; q < 4; ++q) {
                    float pre = accA[q] + bsum[gate * 32 + c];
                    rz[gate * 512 + c * 16 + kb * 4 + q] = sigmoidf_(pre);
                }
            }
            __syncthreads();
            if (gate == 2) {
                int c = (tile - 4) * 16 + (lane & 15);
                #pragma unroll
                for (int q = 0; q < 4; ++q) {
                    int m = kb * 4 + q;
                    float r = rz[c * 16 + m];
                    float z = rz[512 + c * 16 + m];
                    float n = tanhf_(accA[q] + bnih[c] + r * (accB[q] + bnhh[c]));
                    float hn = (1.f - z) * n + z * hprev[q];
                    hprev[q] = hn;
                    hstage[m * 32 + c] = (_Float16)hn;
                }
            }
            __syncthreads();
            if (wave == 4) {
                int r_ = lane >> 2, ch = lane & 3;
                const u64* src = (const u64*)(hstage + r_ * 32 + ch * 8);
                u64* dst = h1 + ((size_t)(s & 3)) * 8192 + (size_t)(m0 + r_) * 128 + slice * 8 + ch * 2;
                st_agent_u64(dst,     src[0]);
                st_agent_u64(dst + 1, src[1]);
                if (lane == 0) st_flag_fenced(myflag, (u32)(s + 1));
                else asm volatile("s_waitcnt vmcnt(0)" ::: "memory");
            }
        }
    } else {
        // ---------------- layer 2 ----------------
        const int lbid  = bid - NWG_L1;
        const int slice = lbid & 31;
        const int hs    = slice * 16;

        half8*    frag   = (half8*)smem;                    // [3][32][64]
        float*    part   = (float*)(smem + 98304);          // [3][16][16]
        float*    rz     = (float*)(smem + 101376);         // [2][16][16]
        _Float16* hstage = (_Float16*)(smem + 103424);      // [16][16]
        float*    bsum   = (float*)(smem + 103936);         // r(16), z(16)
        float*    bnih   = bsum + 32;                       // [16]
        float*    bnhh   = bnih + 16;                       // [16]
        float*    fcs    = bnhh + 16;                       // [16]

        if (tid == 0) st_flag_fenced(myflag, 1u);  // "step 0 done"

        for (int idx = tid; idx < 3 * 32 * 64; idx += 384) {
            int t_ = idx / (32 * 64);
            int ks = (idx / 64) & 31;
            int l  = idx & 63;
            int R  = t_ * 512 + hs + (l & 15);
            half8 w8;
            #pragma unroll
            for (int j = 0; j < 8; ++j) {
                int k = ks * 32 + (l >> 4) * 8 + j;
                float v = (k < HD) ? wih1[(size_t)R * HD + k]
                                   : whh1[(size_t)R * HD + (k - HD)];
                w8[j] = (_Float16)v;
            }
            frag[idx] = w8;
        }
        if (tid < 16) {
            bsum[tid]      = bih1[hs + tid] + bhh1[hs + tid];
            bsum[16 + tid] = bih1[512 + hs + tid] + bhh1[512 + hs + tid];
            bnih[tid]      = bih1[1024 + hs + tid];
            bnhh[tid]      = bhh1[1024 + hs + tid];
            fcs[tid]       = fcw[hs + tid];
        }
        __syncthreads();

        const int gate = wave >> 1;   // 0=r,1=z,2=n
        const int half = wave & 1;    // 0: k from h1 (input), 1: k from h2 (recurrent)
        f32x4 hprev = {0.f, 0.f, 0.f, 0.f};

        for (int s = 1; s <= TSEQ; ++s) {
            if (wave == 0) {
                // L1 WGs (lanes 0-15): need h1 of L1 step s-1 -> flag >= s
                // peers (lanes 16-47): need their h2 slice of step s-1 -> flag >= s
                while (1) {
                    int f = fp ? (int)ld_flag(fp) : 0x7FFFFFFF;
                    if (__all(f >= s)) break;
                    __builtin_amdgcn_s_sleep(1);
                }
                asm volatile("" ::: "memory");
            }
            __syncthreads();

            u64 hq[16][2];
            if (half == 0) {
                const u64* hb = h1 + ((size_t)((s + 3) & 3)) * 8192 + (size_t)(m0 + row) * 128;
                #pragma unroll
                for (int k8 = 0; k8 < 16; ++k8) {
                    const u64* p = hb + k8 * 8 + kb * 2;
                    hq[k8][0] = ld_agent_u64(p);
                    hq[k8][1] = ld_agent_u64(p + 1);
                }
            } else {
                const u64* hb = h2 + ((size_t)((s + 3) & 3)) * 8192 + (size_t)(m0 + row) * 128;
                #pragma unroll
                for (int k8 = 0; k8 < 16; ++k8) {
                    const u64* p = hb + k8 * 8 + kb * 2;
                    hq[k8][0] = ld_agent_u64(p);
                    hq[k8][1] = ld_agent_u64(p + 1);
                }
            }
            f32x4 acc = {0.f, 0.f, 0.f, 0.f};
            #pragma unroll
            for (int k8 = 0; k8 < 16; ++k8) {
                union { u64 q[2]; half8 h; } ua;
                ua.q[0] = hq[k8][0]; ua.q[1] = hq[k8][1];
                acc = __builtin_amdgcn_mfma_f32_16x16x32_f16(ua.h, frag[(gate * 32 + half * 16 + k8) * 64 + lane], acc, 0, 0, 0);
            }

            if (half == 1) {
                int c = lane & 15;
                #pragma unroll
                for (int q = 0; q < 4; ++q) part[gate * 256 + c * 16 + kb * 4 + q] = acc[q];
            }
            __syncthreads();
            if (wave == 0 || wave == 2) {
                int c = lane & 15;
                #pragma unroll
                for (int q = 0; q < 4; ++q) {
                    int m = kb * 4 + q;
                    float pre = acc[q] + part[gate * 256 + c * 16 + m] + bsum[gate * 16 + c];
                    rz[gate * 256 + c * 16 + m] = sigmoidf_(pre);
                }
            }
            __syncthreads();
            if (wave == 4) {
                int c = lane & 15;
                #pragma unroll
                for (int q = 0; q < 4; ++q) {
                    int m = kb * 4 + q;
                    float r = rz[c * 16 + m];
                    float z = rz[256 + c * 16 + m];
                    float n = tanhf_(acc[q] + bnih[c] + r * (part[512 + c * 16 + m] + bnhh[c]));
                    float hn = (1.f - z) * n + z * hprev[q];
                    hprev[q] = hn;
                    hstage[m * 16 + c] = (_Float16)hn;
                }
                if (s == TSEQ) {
                    #pragma unroll
                    for (int q = 0; q < 4; ++q) {
                        float v = hprev[q] * fcs[lane & 15];
                        #pragma unroll
                        for (int off = 1; off < 16; off <<= 1)
                            v += __shfl_xor(v, off, 64);
                        if ((lane & 15) == 0) atomicAdd(out + m0 + kb * 4 + q, v);
                    }
                }
            }
            __syncthreads();
            if (wave == 0 && s < TSEQ) {
                int r_ = lane >> 2, ch = lane & 3;
                u64 v = *(const u64*)(hstage + r_ * 16 + ch * 4);
                u64* dst = h2 + ((size_t)(s & 3)) * 8192 + (size_t)(m0 + r_) * 128 + slice * 4 + ch;
                st_agent_u64(dst, v);
                if (lane == 0) st_flag_fenced(myflag, (u32)(s + 1));
                else asm volatile("s_waitcnt vmcnt(0)" ::: "memory");
            }
        }
    }
}

extern "C" void kernel_launch(void* const* d_in, const int* in_sizes, int n_in,
                              void* d_out, int out_size, void* d_ws, size_t ws_size,
                              hipStream_t stream) {
    (void)in_sizes; (void)n_in; (void)out_size; (void)ws_size;
    const float* x    = (const float*)d_in[0];
    const float* wih0 = (const float*)d_in[1];
    const float* whh0 = (const float*)d_in[2];
    const float* bih0 = (const float*)d_in[3];
    const float* bhh0 = (const float*)d_in[4];
    const float* wih1 = (const float*)d_in[5];
    const float* whh1 = (const float*)d_in[6];
    const float* bih1 = (const float*)d_in[7];
    const float* bhh1 = (const float*)d_in[8];
    const float* fcw  = (const float*)d_in[9];
    const float* fcb  = (const float*)d_in[10];
    float* out = (float*)d_out;
    char* ws = (char*)d_ws;

    hipFuncSetAttribute((const void*)gru_main, hipFuncAttributeMaxDynamicSharedMemorySize, LDS_BYTES);

    gru_init<<<64, 256, 0, stream>>>((u32*)ws, out, fcb);
    gru_main<<<NWG, 384, LDS_BYTES, stream>>>(x, wih0, whh0, bih0, bhh0,
                                              wih1, whh1, bih1, bhh1, fcw, out, ws);
}

// Round 3
// 13655.855 us; speedup vs baseline: 2.6030x; 1.7398x over previous
//
#include <hip/hip_runtime.h>

#define TSEQ 2048
#define NB   64
#define IND  256
#define HD   512

typedef unsigned int u32;
typedef unsigned long long u64;

using half8 = __attribute__((ext_vector_type(8))) _Float16;
using f32x4 = __attribute__((ext_vector_type(4))) float;
using u32x4 = __attribute__((ext_vector_type(4))) u32;
using u32x2 = __attribute__((ext_vector_type(2))) u32;

#define NWG_L1 64
#define NWG_L2 128
#define NWG    (NWG_L1 + NWG_L2)

// ws layout (bytes)
#define WS_FLAGS 0                       // u32[256] (padded to 2KB)
#define WS_H1    2048                    // [4][64][512] f16 = 262144
#define WS_H2    (2048 + 262144)
#define WS_END   (2048 + 524288)

#define LDS_BYTES 38400

__device__ __forceinline__ float sigmoidf_(float x) { return 1.0f / (1.0f + __expf(-x)); }
__device__ __forceinline__ float tanhf_(float x) {
    float ax = __builtin_fabsf(x);
    float e  = __expf(-2.0f * ax);
    float t  = (1.0f - e) / (1.0f + e);
    return x >= 0.0f ? t : -t;
}

// ---- L1+L2-bypass (sc0 sc1) global ops: serviced at the memory-side IF$, so
// cross-XCD visibility is one IF$ round trip. Round-2 counters showed relaxed
// agent atomics were serviced by the (stale) local per-XCD L2 -> ~11us/step
// visibility latency. These asm ops are NOT tracked by the compiler's waitcnt
// logic: every consumer of a bypass load is preceded by an explicit
// s_waitcnt vmcnt(0) + sched_barrier(0).
__device__ __forceinline__ u32x4 ld16_bypass(const void* p) {
    u32x4 r; u64 a = (u64)p;
    asm volatile("global_load_dwordx4 %0, %1, off sc0 sc1" : "=v"(r) : "v"(a) : "memory");
    return r;
}
__device__ __forceinline__ void st16_bypass(void* p, u32x4 v) {
    u64 a = (u64)p;
    asm volatile("global_store_dwordx4 %0, %1, off sc0 sc1" :: "v"(a), "v"(v) : "memory");
}
__device__ __forceinline__ void st8_bypass(void* p, u32x2 v) {
    u64 a = (u64)p;
    asm volatile("global_store_dwordx2 %0, %1, off sc0 sc1" :: "v"(a), "v"(v) : "memory");
}
__device__ __forceinline__ u32 ld4_bypass(const void* p) {
    u32 r; u64 a = (u64)p;
    asm volatile("global_load_dword %0, %1, off sc0 sc1" : "=v"(r) : "v"(a) : "memory");
    return r;
}
__device__ __forceinline__ void st4_bypass(void* p, u32 v) {
    u64 a = (u64)p;
    asm volatile("global_store_dword %0, %1, off sc0 sc1" :: "v"(a), "v"(v) : "memory");
}
#define VMWAIT() do { asm volatile("s_waitcnt vmcnt(0)" ::: "memory"); \
                      __builtin_amdgcn_sched_barrier(0); } while (0)

// LDS row-swizzle for staged h: [16 rows][1024B]; XOR row bits into the 16B-chunk
// index so ds_read_b128 column reads (all rows, same k) hit all banks.
__device__ __forceinline__ int swb(int row, int byteInRow) {
    return row * 1024 + (byteInRow ^ ((row & 7) << 4));
}

// ---------------- init: zero flags + h buffers (to IF$), out = fc_b ----------------
__global__ void gru_init(char* ws, float* out, const float* fcb) {
    size_t n = WS_END / 4;
    size_t i = (size_t)blockIdx.x * blockDim.x + threadIdx.x;
    size_t stride = (size_t)gridDim.x * blockDim.x;
    u32* w32 = (u32*)ws;
    for (; i < n; i += stride) st4_bypass(w32 + i, 0u);
    if (blockIdx.x == 0 && threadIdx.x < NB) {
        u32 b = __float_as_uint(fcb[0]);
        st4_bypass((u32*)out + threadIdx.x, b);
    }
}

// ---------------- persistent GRU ----------------
__global__ void __launch_bounds__(384, 1) gru_main(
    const float* __restrict__ x,
    const float* __restrict__ wih0, const float* __restrict__ whh0,
    const float* __restrict__ bih0, const float* __restrict__ bhh0,
    const float* __restrict__ wih1, const float* __restrict__ whh1,
    const float* __restrict__ bih1, const float* __restrict__ bhh1,
    const float* __restrict__ fcw,
    float* __restrict__ out, char* __restrict__ ws)
{
    extern __shared__ char smem[];
    u32*  flags = (u32*)(ws + WS_FLAGS);
    char* h1b   = ws + WS_H1;   // [4][64][1024B]
    char* h2b   = ws + WS_H2;

    const int tid  = threadIdx.x;
    const int lane = tid & 63;
    const int wave = tid >> 6;
    const int bid  = blockIdx.x;
    const bool isL1 = bid < NWG_L1;
    const int g  = isL1 ? (bid >> 4) : ((bid - NWG_L1) >> 5);
    const int m0 = g * 16;
    const int row = lane & 15;   // batch row within tile (A-operand row/col idx)
    const int kb  = lane >> 4;   // k-block 0..3

    u32* myflag = flags + bid;
    // poll set: 16 L1 flags + 32 L2 flags of this batch-group; lanes 48-63 poll own flag
    u32* fp; int thrbase;
    if (lane < 16)      { fp = flags + (g * 16 + lane);                 thrbase = 0; }
    else if (lane < 48) { fp = flags + (NWG_L1 + g * 32 + (lane - 16)); thrbase = isL1 ? -2 : 0; }
    else                { fp = myflag;                                  thrbase = 0; }

    if (isL1) {
        const int slice = bid & 15;
        const int hs    = slice * 32;

        char*     shH    = smem;                      // staged h1 [16][1024B] swizzled
        float*    rz     = (float*)(smem + 16384);    // [2][32][16]
        _Float16* hstage = (_Float16*)(smem + 20480); // [16][32]

        const int tile = wave;       // 0..5, one 16-col output tile each
        const int gate = tile >> 1;  // 0=r, 1=z, 2=n
        const int cB   = (tile & 1) * 16 + (lane & 15);  // col within 32-col slice
        const int R    = gate * 512 + hs + cB;           // weight row

        // ---- B-fragments into registers (one-time) ----
        half8 wB[24];
        #pragma unroll
        for (int ks = 0; ks < 24; ++ks) {
            int k0 = ks * 32 + kb * 8;
            const float* sp = (k0 < IND) ? (wih0 + (size_t)R * IND + k0)
                                         : (whh0 + (size_t)R * HD + (k0 - IND));
            float4 f0 = *(const float4*)sp, f1 = *(const float4*)(sp + 4);
            wB[ks] = (half8){(_Float16)f0.x,(_Float16)f0.y,(_Float16)f0.z,(_Float16)f0.w,
                             (_Float16)f1.x,(_Float16)f1.y,(_Float16)f1.z,(_Float16)f1.w};
        }
        float bsumv = 0.f, bnihv = 0.f, bnhhv = 0.f;
        if (gate < 2) bsumv = bih0[gate * 512 + hs + cB] + bhh0[gate * 512 + hs + cB];
        else { bnihv = bih0[1024 + hs + cB]; bnhhv = bhh0[1024 + hs + cB]; }

        const float* xrow = x + (size_t)(m0 + row) * (TSEQ * IND);
        float4 xv[16];
        #pragma unroll
        for (int ks = 0; ks < 8; ++ks) {
            const float4* p = (const float4*)(xrow + ks * 32 + kb * 8);
            xv[2 * ks]     = p[0];
            xv[2 * ks + 1] = p[1];
        }
        f32x4 hprev = {0.f, 0.f, 0.f, 0.f};

        for (int s = 0; s < TSEQ; ++s) {
            if (wave == 0 && s > 0) {
                const int thr = s + thrbase;
                while (1) {
                    u32 f = ld4_bypass(fp);
                    asm volatile("s_waitcnt vmcnt(0)" ::: "memory");
                    if (__all((int)f >= thr)) break;
                    __builtin_amdgcn_s_sleep(2);
                }
                __builtin_amdgcn_sched_barrier(0);
            }
            __syncthreads();

            // ---- stage h1[s-1] -> LDS (waves 0-3), overlap with x-part MFMAs ----
            u32x4 sv0, sv1, sv2, sv3; int srow = 0;
            if (wave < 4) {
                srow = wave * 4 + (lane >> 4);
                const char* src = h1b + ((size_t)((s + 3) & 3)) * 65536
                                      + (size_t)(m0 + srow) * 1024 + (lane & 15) * 16;
                sv0 = ld16_bypass(src);
                sv1 = ld16_bypass(src + 256);
                sv2 = ld16_bypass(src + 512);
                sv3 = ld16_bypass(src + 768);
            }

            f32x4 accA = {0.f,0.f,0.f,0.f}, accB = {0.f,0.f,0.f,0.f};
            #pragma unroll
            for (int ks = 0; ks < 8; ++ks) {
                float4 u0 = xv[2 * ks], u1 = xv[2 * ks + 1];
                half8 a = {(_Float16)u0.x,(_Float16)u0.y,(_Float16)u0.z,(_Float16)u0.w,
                           (_Float16)u1.x,(_Float16)u1.y,(_Float16)u1.z,(_Float16)u1.w};
                accA = __builtin_amdgcn_mfma_f32_16x16x32_f16(a, wB[ks], accA, 0, 0, 0);
            }

            if (wave < 4) {
                VMWAIT();
                int bir = (lane & 15) * 16;
                *(u32x4*)(shH + swb(srow, bir))       = sv0;
                *(u32x4*)(shH + swb(srow, bir + 256)) = sv1;
                *(u32x4*)(shH + swb(srow, bir + 512)) = sv2;
                *(u32x4*)(shH + swb(srow, bir + 768)) = sv3;
            }
            // prefetch next x (after ds_write so it doesn't sit in store-drain waits)
            if (s + 1 < TSEQ) {
                #pragma unroll
                for (int ks = 0; ks < 8; ++ks) {
                    const float4* p = (const float4*)(xrow + (size_t)(s + 1) * IND + ks * 32 + kb * 8);
                    xv[2 * ks]     = p[0];
                    xv[2 * ks + 1] = p[1];
                }
            }
            __syncthreads();

            // ---- h-part MFMAs from staged LDS ----
            #pragma unroll
            for (int k8 = 0; k8 < 16; ++k8) {
                half8 a = *(const half8*)(shH + swb(row, k8 * 64 + kb * 16));
                if (gate == 2)
                    accB = __builtin_amdgcn_mfma_f32_16x16x32_f16(a, wB[8 + k8], accB, 0, 0, 0);
                else
                    accA = __builtin_amdgcn_mfma_f32_16x16x32_f16(a, wB[8 + k8], accA, 0, 0, 0);
            }

            // ---- epilogue ----
            if (gate < 2) {
                #pragma unroll
                for (int q = 0; q < 4; ++q)
                    rz[gate * 512 + cB * 16 + kb * 4 + q] = sigmoidf_(accA[q] + bsumv);
            }
            __syncthreads();
            if (gate == 2) {
                #pragma unroll
                for (int q = 0; q < 4; ++q) {
                    int m = kb * 4 + q;
                    float r = rz[cB * 16 + m];
                    float z = rz[512 + cB * 16 + m];
                    float n = tanhf_(accA[q] + bnihv + r * (accB[q] + bnhhv));
                    float hn = (1.f - z) * n + z * hprev[q];
                    hprev[q] = hn;
                    hstage[m * 32 + cB] = (_Float16)hn;
                }
            }
            __syncthreads();
            if (wave == 4) {
                int r_ = lane >> 2, ch = lane & 3;
                u32x4 v = *(const u32x4*)(hstage + r_ * 32 + ch * 8);
                char* dst = h1b + ((size_t)(s & 3)) * 65536
                                + (size_t)(m0 + r_) * 1024 + slice * 64 + ch * 16;
                st16_bypass(dst, v);
                asm volatile("s_waitcnt vmcnt(0)" ::: "memory");
                if (lane == 0) st4_bypass(myflag, (u32)(s + 1));
            }
        }
    } else {
        // ---------------- layer 2 ----------------
        const int lbid  = bid - NWG_L1;
        const int slice = lbid & 31;
        const int hs    = slice * 16;

        char*     shH1   = smem;                      // staged h1 [16][1024B] swizzled
        char*     shH2   = smem + 16384;              // staged h2
        float*    part   = (float*)(smem + 32768);    // [3][16][16]
        float*    rz     = (float*)(smem + 35840);    // [2][16][16]
        _Float16* hstage = (_Float16*)(smem + 37888); // [16][16]

        const int gate = wave >> 1;   // 0=r,1=z,2=n
        const int half = wave & 1;    // 0: k from h1, 1: k from h2
        const int cB   = lane & 15;
        const int R    = gate * 512 + hs + cB;

        half8 wB[16];
        #pragma unroll
        for (int ks = 0; ks < 16; ++ks) {
            int kg = half * 512 + ks * 32 + kb * 8;
            const float* sp = (kg < HD) ? (wih1 + (size_t)R * HD + kg)
                                        : (whh1 + (size_t)R * HD + (kg - HD));
            float4 f0 = *(const float4*)sp, f1 = *(const float4*)(sp + 4);
            wB[ks] = (half8){(_Float16)f0.x,(_Float16)f0.y,(_Float16)f0.z,(_Float16)f0.w,
                             (_Float16)f1.x,(_Float16)f1.y,(_Float16)f1.z,(_Float16)f1.w};
        }
        float bsumv = 0.f, bnihv = 0.f, bnhhv = 0.f, fcsv = 0.f;
        if (wave == 0 || wave == 2) bsumv = bih1[gate * 512 + hs + cB] + bhh1[gate * 512 + hs + cB];
        if (wave == 4) { bnihv = bih1[1024 + hs + cB]; bnhhv = bhh1[1024 + hs + cB]; fcsv = fcw[hs + cB]; }
        f32x4 hprev = {0.f, 0.f, 0.f, 0.f};

        if (tid == 0) st4_bypass(myflag, 1u);  // "step 0 done"

        for (int s = 1; s <= TSEQ; ++s) {
            if (wave == 0) {
                while (1) {
                    u32 f = ld4_bypass(fp);
                    asm volatile("s_waitcnt vmcnt(0)" ::: "memory");
                    if (__all((int)f >= s)) break;
                    __builtin_amdgcn_s_sleep(2);
                }
                __builtin_amdgcn_sched_barrier(0);
            }
            __syncthreads();

            // ---- stage h1[s-1] (waves 0-3) and h2[s-1] (waves 4-5) -> LDS ----
            if (wave < 4) {
                int srow = wave * 4 + (lane >> 4);
                const char* src = h1b + ((size_t)((s + 3) & 3)) * 65536
                                      + (size_t)(m0 + srow) * 1024 + (lane & 15) * 16;
                u32x4 v0 = ld16_bypass(src);
                u32x4 v1 = ld16_bypass(src + 256);
                u32x4 v2 = ld16_bypass(src + 512);
                u32x4 v3 = ld16_bypass(src + 768);
                VMWAIT();
                int bir = (lane & 15) * 16;
                *(u32x4*)(shH1 + swb(srow, bir))       = v0;
                *(u32x4*)(shH1 + swb(srow, bir + 256)) = v1;
                *(u32x4*)(shH1 + swb(srow, bir + 512)) = v2;
                *(u32x4*)(shH1 + swb(srow, bir + 768)) = v3;
            } else {
                int srow = (wave - 4) * 8 + (lane >> 3);
                const char* src = h2b + ((size_t)((s + 3) & 3)) * 65536
                                      + (size_t)(m0 + srow) * 1024 + (lane & 7) * 16;
                u32x4 v0 = ld16_bypass(src);
                u32x4 v1 = ld16_bypass(src + 128);
                u32x4 v2 = ld16_bypass(src + 256);
                u32x4 v3 = ld16_bypass(src + 384);
                u32x4 v4 = ld16_bypass(src + 512);
                u32x4 v5 = ld16_bypass(src + 640);
                u32x4 v6 = ld16_bypass(src + 768);
                u32x4 v7 = ld16_bypass(src + 896);
                VMWAIT();
                int bir = (lane & 7) * 16;
                *(u32x4*)(shH2 + swb(srow, bir))       = v0;
                *(u32x4*)(shH2 + swb(srow, bir + 128)) = v1;
                *(u32x4*)(shH2 + swb(srow, bir + 256)) = v2;
                *(u32x4*)(shH2 + swb(srow, bir + 384)) = v3;
                *(u32x4*)(shH2 + swb(srow, bir + 512)) = v4;
                *(u32x4*)(shH2 + swb(srow, bir + 640)) = v5;
                *(u32x4*)(shH2 + swb(srow, bir + 768)) = v6;
                *(u32x4*)(shH2 + swb(srow, bir + 896)) = v7;
            }
            __syncthreads();

            const char* hb = half ? shH2 : shH1;
            f32x4 acc = {0.f, 0.f, 0.f, 0.f};
            #pragma unroll
            for (int k8 = 0; k8 < 16; ++k8) {
                half8 a = *(const half8*)(hb + swb(row, k8 * 64 + kb * 16));
                acc = __builtin_amdgcn_mfma_f32_16x16x32_f16(a, wB[k8], acc, 0, 0, 0);
            }

            if (half == 1) {
                #pragma unroll
                for (int q = 0; q < 4; ++q) part[gate * 256 + cB * 16 + kb * 4 + q] = acc[q];
            }
            __syncthreads();
            if (wave == 0 || wave == 2) {
                #pragma unroll
                for (int q = 0; q < 4; ++q) {
                    int m = kb * 4 + q;
                    float pre = acc[q] + part[gate * 256 + cB * 16 + m] + bsumv;
                    rz[gate * 256 + cB * 16 + m] = sigmoidf_(pre);
                }
            }
            __syncthreads();
            if (wave == 4) {
                #pragma unroll
                for (int q = 0; q < 4; ++q) {
                    int m = kb * 4 + q;
                    float r = rz[cB * 16 + m];
                    float z = rz[256 + cB * 16 + m];
                    float n = tanhf_(acc[q] + bnihv + r * (part[512 + cB * 16 + m] + bnhhv));
                    float hn = (1.f - z) * n + z * hprev[q];
                    hprev[q] = hn;
                    hstage[m * 16 + cB] = (_Float16)hn;
                }
                if (s == TSEQ) {
                    #pragma unroll
                    for (int q = 0; q < 4; ++q) {
                        float v = hprev[q] * fcsv;
                        #pragma unroll
                        for (int off = 1; off < 16; off <<= 1)
                            v += __shfl_xor(v, off, 64);
                        if ((lane & 15) == 0) atomicAdd(out + m0 + kb * 4 + q, v);
                    }
                }
            }
            __syncthreads();
            if (wave == 0 && s < TSEQ) {
                int r_ = lane >> 2, ch = lane & 3;
                u32x2 v = *(const u32x2*)(hstage + r_ * 16 + ch * 4);
                char* dst = h2b + ((size_t)(s & 3)) * 65536
                                + (size_t)(m0 + r_) * 1024 + slice * 32 + ch * 8;
                st8_bypass(dst, v);
                asm volatile("s_waitcnt vmcnt(0)" ::: "memory");
                if (lane == 0) st4_bypass(myflag, (u32)(s + 1));
            }
        }
    }
}

extern "C" void kernel_launch(void* const* d_in, const int* in_sizes, int n_in,
                              void* d_out, int out_size, void* d_ws, size_t ws_size,
                              hipStream_t stream) {
    (void)in_sizes; (void)n_in; (void)out_size; (void)ws_size;
    const float* x    = (const float*)d_in[0];
    const float* wih0 = (const float*)d_in[1];
    const float* whh0 = (const float*)d_in[2];
    const float* bih0 = (const float*)d_in[3];
    const float* bhh0 = (const float*)d_in[4];
    const float* wih1 = (const float*)d_in[5];
    const float* whh1 = (const float*)d_in[6];
    const float* bih1 = (const float*)d_in[7];
    const float* bhh1 = (const float*)d_in[8];
    const float* fcw  = (const float*)d_in[9];
    const float* fcb  = (const float*)d_in[10];
    float* out = (float*)d_out;
    char* ws = (char*)d_ws;

    gru_init<<<64, 256, 0, stream>>>(ws, out, fcb);
    gru_main<<<NWG, 384, LDS_BYTES, stream>>>(x, wih0, whh0, bih0, bhh0,
                                              wih1, whh1, bih1, bhh1, fcw, out, ws);
}